// Round 18
// baseline (274.312 us; speedup 1.0000x reference)
//
#include <hip/hip_runtime.h>
#include <hip/hip_bf16.h>

typedef _Float16 f16x8 __attribute__((ext_vector_type(8)));
typedef float f32x4 __attribute__((ext_vector_type(4)));

#define MFMA16(a, b, c) __builtin_amdgcn_mfma_f32_16x16x32_f16(a, b, c, 0, 0, 0)

__device__ __forceinline__ void load_lds16(const void* g, void* l) {
  __builtin_amdgcn_global_load_lds(
      (__attribute__((address_space(1))) void*)g,
      (__attribute__((address_space(3))) void*)l, 16, 0, 0);
}

// ============ prep kernel: cvt x, cvt ctx, 4 weight transposes, Vtg pad fill ============
__global__ __launch_bounds__(256) void k_prep(const float* __restrict__ x,
                                              const float* __restrict__ ctx,
                                              const float* __restrict__ Wq,
                                              const float* __restrict__ Wk,
                                              const float* __restrict__ Wv,
                                              const float* __restrict__ Wo,
                                              _Float16* __restrict__ xh,
                                              _Float16* __restrict__ ctxh,
                                              _Float16* __restrict__ Wqt,
                                              _Float16* __restrict__ Wkt,
                                              _Float16* __restrict__ Wvt,
                                              _Float16* __restrict__ Wot,
                                              _Float16* __restrict__ Vtg) {
  __shared__ float tile[64][65];
  const int b = blockIdx.x, t = threadIdx.x;

  if (b < 4096) {  // cvt x
    for (int i = b * 256 + t; i < 4194304; i += 4096 * 256) {
      const float4* p = (const float4*)(x + (size_t)i * 8);
      float4 a = p[0], c = p[1];
      f16x8 v = {(_Float16)a.x, (_Float16)a.y, (_Float16)a.z, (_Float16)a.w,
                 (_Float16)c.x, (_Float16)c.y, (_Float16)c.z, (_Float16)c.w};
      *(f16x8*)(xh + (size_t)i * 8) = v;
    }
    return;
  }
  if (b < 4327) {  // cvt ctx
    int i = (b - 4096) * 256 + t;
    const float4* p = (const float4*)(ctx + (size_t)i * 8);
    float4 a = p[0], c = p[1];
    f16x8 v = {(_Float16)a.x, (_Float16)a.y, (_Float16)a.z, (_Float16)a.w,
               (_Float16)c.x, (_Float16)c.y, (_Float16)c.z, (_Float16)c.w};
    *(f16x8*)(ctxh + (size_t)i * 8) = v;
    return;
  }
  if (b >= 5223) {  // zero Vtg pad region
    int i = (b - 5223) * 256 + t;
    ((f16x8*)Vtg)[i] = f16x8{};
    return;
  }
  const float* tin;
  _Float16* tout;
  int TK, TN, i;
  if (b < 4583)      { tin = Wq; tout = Wqt; TK = 1024; TN = 1024; i = b - 4327; }
  else if (b < 4775) { tin = Wk; tout = Wkt; TK = 768;  TN = 1024; i = b - 4583; }
  else if (b < 4967) { tin = Wv; tout = Wvt; TK = 768;  TN = 1024; i = b - 4775; }
  else               { tin = Wo; tout = Wot; TK = 1024; TN = 1024; i = b - 4967; }
  int n0 = (i & 15) * 64, k0 = (i >> 4) * 64;
  {
    int nn = t & 63, kb = t >> 6;
#pragma unroll
    for (int s = 0; s < 16; ++s) {
      int kk = kb + s * 4;
      tile[kk][nn] = tin[(size_t)(k0 + kk) * TN + n0 + nn];
    }
  }
  __syncthreads();
  {
    int kk = t & 63, nb = t >> 6;
#pragma unroll
    for (int s = 0; s < 16; ++s) {
      int nn = nb + s * 4;
      tout[(size_t)(n0 + nn) * TK + k0 + kk] = (_Float16)tile[kk][nn];
    }
  }
}

// ---------------- K/V projection: ctxh[616][768] @ W^T -> heads ----------------
__global__ __launch_bounds__(64) void k_kvproj(const _Float16* __restrict__ ctxh,
                                               const _Float16* __restrict__ Wkt,
                                               const _Float16* __restrict__ Wvt,
                                               _Float16* __restrict__ Kg,
                                               _Float16* __restrict__ Vtg) {
  int mt = blockIdx.x, nt = blockIdx.y;
  int lane = threadIdx.x;
  int l15 = lane & 15, lhi = lane >> 4;
  int arow = mt * 16 + l15;
  if (arow > 615) arow = 615;  // clamp; masked at write
  const _Float16* ap = ctxh + (size_t)arow * 768 + lhi * 8;
  const _Float16* kp = Wkt + (size_t)(nt * 16 + l15) * 768 + lhi * 8;
  const _Float16* vp = Wvt + (size_t)(nt * 16 + l15) * 768 + lhi * 8;
  f32x4 ak = {0.f, 0.f, 0.f, 0.f}, av = {0.f, 0.f, 0.f, 0.f};
#pragma unroll 4
  for (int ks = 0; ks < 24; ++ks) {
    f16x8 a = *(const f16x8*)(ap + ks * 32);
    f16x8 bk = *(const f16x8*)(kp + ks * 32);
    f16x8 bv = *(const f16x8*)(vp + ks * 32);
    ak = MFMA16(a, bk, ak);
    av = MFMA16(a, bv, av);
  }
  int n = nt * 16 + l15, h = n >> 6, d = n & 63;
#pragma unroll
  for (int j = 0; j < 4; ++j) {
    int gm = mt * 16 + lhi * 4 + j;
    if (gm < 616) {
      int b = gm / 77, m = gm - b * 77;
      Kg[((size_t)(b * 16 + h) * 77 + m) * 64 + d] = (_Float16)ak[j];
      Vtg[((size_t)(b * 16 + h) * 64 + d) * 128 + m] = (_Float16)av[j];
    }
  }
}

// ====== 128x256 GEMM, 3-buffer ring (R6 structure, pointer-XOR bug FIXED) ======
// BK=64, 512 thr = 8 waves (2M x 4N), per-wave C = 64x64 (4x4 16x16 frags).
// Ring: 3 bufs x (A 16KB + B 32KB) = 144KB. Tile t reads buf[t%3]; tile t+2 is
// staged into the DEAD buffer -> ONE barrier + ONE COUNTED vmcnt(6) per tile
// (T4: never drain to 0 in the main loop). All LDS fragment reads are INT
// OFFSETS into the __shared__ array (cs0/cs1) — R6/R7's (size_t)ptr^64 made
// half the reads lower to FLAT ops, which count against vmcnt and silently
// serialized the counted-vmcnt pipeline (R7: 1.83x). Swizzle: store chunk
// c^(r&7), pre-swizzled global source, same XOR on reads (conflict-free, R6=0).
// MODE 0: + fused attention epilogue (wave owns 64 q-rows x head tn*4+wc).
// MODE 1: f32 out + bias.
template <int MODE>
__global__ __launch_bounds__(512, 2) void k_gemmR(const _Float16* __restrict__ A,
                                                  const _Float16* __restrict__ Bt,
                                                  void* __restrict__ Cout,
                                                  const float* __restrict__ bias,
                                                  const _Float16* __restrict__ Kg,
                                                  const _Float16* __restrict__ Vtg,
                                                  int M, int N, int K) {
  __shared__ __align__(16) char lds[147456];
  const int t = threadIdx.x, wid = t >> 6, lane = t & 63;
  const int wr = wid >> 2, wc = wid & 3;  // 2M x 4N wave grid
  const int l15 = lane & 15, lhi = lane >> 4;

  // T1: bijective XCD swizzle (nwg % 8 == 0)
  int nwg = gridDim.x, bid = blockIdx.x;
  int wg = ((nwg & 7) == 0) ? ((bid & 7) * (nwg >> 3) + (bid >> 3)) : bid;
  const int nTN = N >> 8;
  const int tm = wg / nTN, tn = wg % nTN;

  const _Float16* Ag = A + (size_t)tm * 128 * K;
  const _Float16* Bg = Bt + (size_t)tn * 256 * K;
  const size_t stg = (size_t)(wid * 8 + (lane >> 3)) * K +
                     (size_t)(((lane & 7) ^ ((lane >> 3) & 7)) * 8);
  const int dstg = wid * 1024;  // linear wave dest (HW adds lane*16)

  // read swizzle as int offsets: chunk(kk) = (kk*4 + lhi) ^ (l15&7)
  const int x7 = l15 & 7;
  const int cs0 = (lhi ^ x7) << 4;
  const int cs1 = ((4 + lhi) ^ x7) << 4;
  const int aoff = (wr * 64 + l15) * 128;          // + mf*2048 + cs{kk}
  const int boff = 16384 + (wc * 64 + l15) * 128;  // + nf*2048 + cs{kk}

  f32x4 acc[4][4];
#pragma unroll
  for (int i = 0; i < 4; ++i)
#pragma unroll
    for (int j = 0; j < 4; ++j) acc[i][j] = f32x4{0.f, 0.f, 0.f, 0.f};
  f16x8 a0[4], a1[4], b0[4], b1[4];

#define STG_TILE(T, BUF)                                                          \
  {                                                                               \
    const size_t co = (size_t)(T) * 64;                                           \
    char* d_ = lds + (BUF) * 49152 + dstg;                                        \
    load_lds16(Ag + stg + co, d_);                                                \
    load_lds16(Ag + stg + (size_t)64 * K + co, d_ + 8192);                        \
    load_lds16(Bg + stg + co, d_ + 16384);                                        \
    load_lds16(Bg + stg + (size_t)64 * K + co, d_ + 16384 + 8192);                \
    load_lds16(Bg + stg + (size_t)128 * K + co, d_ + 16384 + 16384);              \
    load_lds16(Bg + stg + (size_t)192 * K + co, d_ + 16384 + 24576);              \
  }
#define VM6 asm volatile("s_waitcnt vmcnt(6)" ::: "memory")
#define VM0 asm volatile("s_waitcnt vmcnt(0)" ::: "memory")
#define BAR __builtin_amdgcn_s_barrier()

  const int nT = K >> 6;  // 16 for K=1024 (needs nT >= 3)

  STG_TILE(0, 0);
  STG_TILE(1, 1);

  int bufR = 0;
  for (int tt = 0; tt < nT; ++tt) {
    if (tt == nT - 1) { VM0; } else { VM6; }  // counted: retire tile tt's 6
    BAR;                                      // publish all waves' gloads
    if (tt < nT - 2) {
      int bufS = bufR + 2; if (bufS >= 3) bufS -= 3;
      STG_TILE(tt + 2, bufS);                 // into dead buffer
    }
    const int base = bufR * 49152;
    // frag reads: pure int-offset GEPs into lds[] (LDS addrspace preserved)
#pragma unroll
    for (int mf = 0; mf < 4; ++mf) {
      a0[mf] = *(const f16x8*)&lds[base + aoff + mf * 2048 + cs0];
      a1[mf] = *(const f16x8*)&lds[base + aoff + mf * 2048 + cs1];
    }
#pragma unroll
    for (int nf = 0; nf < 4; ++nf) {
      b0[nf] = *(const f16x8*)&lds[base + boff + nf * 2048 + cs0];
      b1[nf] = *(const f16x8*)&lds[base + boff + nf * 2048 + cs1];
    }
    __builtin_amdgcn_s_setprio(1);
#pragma unroll
    for (int mf = 0; mf < 4; ++mf)
#pragma unroll
      for (int nf = 0; nf < 4; ++nf) {
        acc[mf][nf] = MFMA16(a0[mf], b0[nf], acc[mf][nf]);
        acc[mf][nf] = MFMA16(a1[mf], b1[nf], acc[mf][nf]);
      }
    __builtin_amdgcn_s_setprio(0);
    bufR = (bufR == 2) ? 0 : bufR + 1;
  }

  if (MODE == 1) {
    // ---- plain epilogue: f32 + bias
    const long rbase = (long)tm * 128 + wr * 64;
    const int cbase = tn * 256 + wc * 64;
#pragma unroll
    for (int mf = 0; mf < 4; ++mf)
#pragma unroll
      for (int nf = 0; nf < 4; ++nf) {
        int c = cbase + nf * 16 + l15;
        float bv = bias[c];
#pragma unroll
        for (int j = 0; j < 4; ++j) {
          long r = rbase + mf * 16 + lhi * 4 + j;
          ((float*)Cout)[r * N + c] = acc[mf][nf][j] + bv;
        }
      }
    return;
  }

  // =================== MODE 0: fused attention epilogue ===================
  // wave owns q-rows [tm*128 + wr*64, +64) x head h = tn*4 + wc.
  BAR;  // all waves done with ring LDS before repurposing

  const int h = tn * 4 + wc;
  const int bh = (tm >> 5) * 16 + h;  // batch = tm*128/4096 = tm>>5
  const _Float16* Kgp = Kg + (size_t)bh * (77 * 64);
  const _Float16* Vgp = Vtg + (size_t)bh * (64 * 128);

  // hoisted mf-invariant K/V register loads (latency hides under Q-dump)
  f16x8 kf[5][2];
#pragma unroll
  for (int ct = 0; ct < 5; ++ct) {
    int m = ct * 16 + l15;
    kf[ct][0] = *(const f16x8*)(Kgp + m * 64 + lhi * 8);
    kf[ct][1] = *(const f16x8*)(Kgp + m * 64 + 32 + lhi * 8);
  }
  f16x8 vf[3][4];
#pragma unroll
  for (int ks = 0; ks < 3; ++ks)
#pragma unroll
    for (int dt = 0; dt < 4; ++dt) {
      int d = dt * 16 + l15;
      vf[ks][dt] = *(const f16x8*)(Vgp + d * 128 + ks * 32 + lhi * 8);
    }

  // dump Q (f32 acc -> f16) into per-wave 8KB LDS: [64 rows][64 d]
  const int qbase = wid * 8192;
#pragma unroll
  for (int mf = 0; mf < 4; ++mf)
#pragma unroll
    for (int nf = 0; nf < 4; ++nf)
#pragma unroll
      for (int j = 0; j < 4; ++j) {
        int row = mf * 16 + lhi * 4 + j;
        int d = nf * 16 + l15;
        int by = (row * 128 + d * 2) ^ ((row & 7) << 4);
        *(_Float16*)&lds[qbase + by] = (_Float16)acc[mf][nf][j];
      }

  // per-wave P region (4KB) at 64KB + wid*4KB; zero once (covers m 80..95 pad)
  const int pbase = 65536 + wid * 4096;
#pragma unroll
  for (int i = 0; i < 4; ++i)
    *(f16x8*)&lds[pbase + lane * 64 + i * 16] = f16x8{};
  // wave-private below; no barrier needed.

  const long orow0 = (long)tm * 128 + wr * 64;
  _Float16* aOut = (_Float16*)Cout;

  for (int mf = 0; mf < 4; ++mf) {
    const int qm = qbase + mf * 2048 + l15 * 128;
    f16x8 q0 = *(const f16x8*)&lds[qm + cs0];
    f16x8 q1 = *(const f16x8*)&lds[qm + cs1];

    float e[5][4];
    float mx[4] = {-1e30f, -1e30f, -1e30f, -1e30f};
    __builtin_amdgcn_s_setprio(1);
#pragma unroll
    for (int ct = 0; ct < 5; ++ct) {
      f32x4 s = {0.f, 0.f, 0.f, 0.f};
      s = MFMA16(q0, kf[ct][0], s);
      s = MFMA16(q1, kf[ct][1], s);
      bool valid = (ct * 16 + l15) < 77;
#pragma unroll
      for (int j = 0; j < 4; ++j) {
        float v = valid ? s[j] * 0.125f : -1e30f;
        e[ct][j] = v;
        mx[j] = fmaxf(mx[j], v);
      }
    }
    __builtin_amdgcn_s_setprio(0);
#pragma unroll
    for (int off = 1; off < 16; off <<= 1)
#pragma unroll
      for (int j = 0; j < 4; ++j) mx[j] = fmaxf(mx[j], __shfl_xor(mx[j], off, 64));

    float sm[4] = {0.f, 0.f, 0.f, 0.f};
#pragma unroll
    for (int ct = 0; ct < 5; ++ct)
#pragma unroll
      for (int j = 0; j < 4; ++j) {
        float ev = __expf(e[ct][j] - mx[j]);
        e[ct][j] = ev;
        sm[j] += ev;
      }
#pragma unroll
    for (int ct = 0; ct < 5; ++ct) {
      int m = ct * 16 + l15;
#pragma unroll
      for (int j = 0; j < 4; ++j) {
        int r = lhi * 4 + j;
        *(_Float16*)&lds[pbase + ((r * 256 + m * 2) ^ ((r & 7) << 4))] =
            (_Float16)e[ct][j];
      }
    }
#pragma unroll
    for (int off = 1; off < 16; off <<= 1)
#pragma unroll
      for (int j = 0; j < 4; ++j) sm[j] += __shfl_xor(sm[j], off, 64);
    float rs[4];
#pragma unroll
    for (int j = 0; j < 4; ++j) rs[j] = 1.0f / sm[j];

    f32x4 o[4] = {{0.f,0.f,0.f,0.f},{0.f,0.f,0.f,0.f},{0.f,0.f,0.f,0.f},{0.f,0.f,0.f,0.f}};
    __builtin_amdgcn_s_setprio(1);
#pragma unroll
    for (int ks = 0; ks < 3; ++ks) {
      int m0b = ks * 64 + lhi * 16;
      f16x8 pa = *(const f16x8*)&lds[pbase + ((l15 * 256 + m0b) ^ ((l15 & 7) << 4))];
#pragma unroll
      for (int dt = 0; dt < 4; ++dt)
        o[dt] = MFMA16(pa, vf[ks][dt], o[dt]);
    }
    __builtin_amdgcn_s_setprio(0);
    _Float16* op = aOut + (size_t)(orow0 + mf * 16 + lhi * 4) * 1024 + h * 64;
#pragma unroll
    for (int dt = 0; dt < 4; ++dt)
#pragma unroll
      for (int j = 0; j < 4; ++j)
        op[(size_t)j * 1024 + dt * 16 + l15] = (_Float16)(o[dt][j] * rs[j]);
  }
#undef STG_TILE
#undef VM6
#undef VM0
#undef BAR
}

extern "C" void kernel_launch(void* const* d_in, const int* in_sizes, int n_in,
                              void* d_out, int out_size, void* d_ws, size_t ws_size,
                              hipStream_t stream) {
  const float* x   = (const float*)d_in[0];
  const float* ctx = (const float*)d_in[1];
  const float* Wq  = (const float*)d_in[2];
  const float* Wk  = (const float*)d_in[3];
  const float* Wv  = (const float*)d_in[4];
  const float* Wo  = (const float*)d_in[5];
  const float* bo  = (const float*)d_in[6];

  char* ws = (char*)d_ws;
  _Float16* xh   = (_Float16*)(ws + 0);           // [32768][1024] x-f16
  _Float16* Wqt  = (_Float16*)(ws + 67108864);    // [1024][1024]
  _Float16* Wkt  = (_Float16*)(ws + 69206016);    // [1024][768]
  _Float16* Wvt  = (_Float16*)(ws + 70778880);    // [1024][768]
  _Float16* Wot  = (_Float16*)(ws + 72351744);    // [1024][1024]
  _Float16* ctxh = (_Float16*)(ws + 74448896);    // [616][768]
  _Float16* Kg   = (_Float16*)(ws + 75395072);    // [128][77][64]
  _Float16* Vtg  = (_Float16*)(ws + 76656640);    // [128][64][128]
  _Float16* aOut = (_Float16*)(ws + 78774272);    // [32768][1024] attnOut

  k_prep<<<5735, 256, 0, stream>>>(x, ctx, Wq, Wk, Wv, Wo,
                                   xh, ctxh, Wqt, Wkt, Wvt, Wot, Vtg);
  k_kvproj<<<dim3(39, 64), 64, 0, stream>>>(ctxh, Wkt, Wvt, Kg, Vtg);
  // GEMM1 + fused attention: ring K-loop; grid (32768/128)*(1024/256) = 1024
  k_gemmR<0><<<dim3(1024), dim3(512), 0, stream>>>(xh, Wqt, (void*)aOut, nullptr,
                                                   Kg, Vtg, 32768, 1024, 1024);
  // GEMM2: O projection + bias -> d_out (f32)
  k_gemmR<1><<<dim3(1024), dim3(512), 0, stream>>>(aOut, Wot, d_out, bo,
                                                   nullptr, nullptr, 32768, 1024, 1024);
}

// Round 19
// 242.899 us; speedup vs baseline: 1.1293x; 1.1293x over previous
//
#include <hip/hip_runtime.h>
#include <hip/hip_bf16.h>

typedef _Float16 f16x8 __attribute__((ext_vector_type(8)));
typedef float f32x4 __attribute__((ext_vector_type(4)));

#define MFMA16(a, b, c) __builtin_amdgcn_mfma_f32_16x16x32_f16(a, b, c, 0, 0, 0)

__device__ __forceinline__ void load_lds16(const void* g, void* l) {
  __builtin_amdgcn_global_load_lds(
      (__attribute__((address_space(1))) void*)g,
      (__attribute__((address_space(3))) void*)l, 16, 0, 0);
}

// ============ prep kernel: cvt x, cvt ctx, 4 weight transposes, Vtg pad fill ============
__global__ __launch_bounds__(256) void k_prep(const float* __restrict__ x,
                                              const float* __restrict__ ctx,
                                              const float* __restrict__ Wq,
                                              const float* __restrict__ Wk,
                                              const float* __restrict__ Wv,
                                              const float* __restrict__ Wo,
                                              _Float16* __restrict__ xh,
                                              _Float16* __restrict__ ctxh,
                                              _Float16* __restrict__ Wqt,
                                              _Float16* __restrict__ Wkt,
                                              _Float16* __restrict__ Wvt,
                                              _Float16* __restrict__ Wot,
                                              _Float16* __restrict__ Vtg) {
  __shared__ float tile[64][65];
  const int b = blockIdx.x, t = threadIdx.x;

  if (b < 4096) {  // cvt x
    for (int i = b * 256 + t; i < 4194304; i += 4096 * 256) {
      const float4* p = (const float4*)(x + (size_t)i * 8);
      float4 a = p[0], c = p[1];
      f16x8 v = {(_Float16)a.x, (_Float16)a.y, (_Float16)a.z, (_Float16)a.w,
                 (_Float16)c.x, (_Float16)c.y, (_Float16)c.z, (_Float16)c.w};
      *(f16x8*)(xh + (size_t)i * 8) = v;
    }
    return;
  }
  if (b < 4327) {  // cvt ctx
    int i = (b - 4096) * 256 + t;
    const float4* p = (const float4*)(ctx + (size_t)i * 8);
    float4 a = p[0], c = p[1];
    f16x8 v = {(_Float16)a.x, (_Float16)a.y, (_Float16)a.z, (_Float16)a.w,
               (_Float16)c.x, (_Float16)c.y, (_Float16)c.z, (_Float16)c.w};
    *(f16x8*)(ctxh + (size_t)i * 8) = v;
    return;
  }
  if (b >= 5223) {  // zero Vtg pad region
    int i = (b - 5223) * 256 + t;
    ((f16x8*)Vtg)[i] = f16x8{};
    return;
  }
  const float* tin;
  _Float16* tout;
  int TK, TN, i;
  if (b < 4583)      { tin = Wq; tout = Wqt; TK = 1024; TN = 1024; i = b - 4327; }
  else if (b < 4775) { tin = Wk; tout = Wkt; TK = 768;  TN = 1024; i = b - 4583; }
  else if (b < 4967) { tin = Wv; tout = Wvt; TK = 768;  TN = 1024; i = b - 4775; }
  else               { tin = Wo; tout = Wot; TK = 1024; TN = 1024; i = b - 4967; }
  int n0 = (i & 15) * 64, k0 = (i >> 4) * 64;
  {
    int nn = t & 63, kb = t >> 6;
#pragma unroll
    for (int s = 0; s < 16; ++s) {
      int kk = kb + s * 4;
      tile[kk][nn] = tin[(size_t)(k0 + kk) * TN + n0 + nn];
    }
  }
  __syncthreads();
  {
    int kk = t & 63, nb = t >> 6;
#pragma unroll
    for (int s = 0; s < 16; ++s) {
      int nn = nb + s * 4;
      tout[(size_t)(n0 + nn) * TK + k0 + kk] = (_Float16)tile[kk][nn];
    }
  }
}

// ---------------- K/V projection: ctxh[616][768] @ W^T -> heads ----------------
__global__ __launch_bounds__(64) void k_kvproj(const _Float16* __restrict__ ctxh,
                                               const _Float16* __restrict__ Wkt,
                                               const _Float16* __restrict__ Wvt,
                                               _Float16* __restrict__ Kg,
                                               _Float16* __restrict__ Vtg) {
  int mt = blockIdx.x, nt = blockIdx.y;
  int lane = threadIdx.x;
  int l15 = lane & 15, lhi = lane >> 4;
  int arow = mt * 16 + l15;
  if (arow > 615) arow = 615;  // clamp; masked at write
  const _Float16* ap = ctxh + (size_t)arow * 768 + lhi * 8;
  const _Float16* kp = Wkt + (size_t)(nt * 16 + l15) * 768 + lhi * 8;
  const _Float16* vp = Wvt + (size_t)(nt * 16 + l15) * 768 + lhi * 8;
  f32x4 ak = {0.f, 0.f, 0.f, 0.f}, av = {0.f, 0.f, 0.f, 0.f};
#pragma unroll 4
  for (int ks = 0; ks < 24; ++ks) {
    f16x8 a = *(const f16x8*)(ap + ks * 32);
    f16x8 bk = *(const f16x8*)(kp + ks * 32);
    f16x8 bv = *(const f16x8*)(vp + ks * 32);
    ak = MFMA16(a, bk, ak);
    av = MFMA16(a, bv, av);
  }
  int n = nt * 16 + l15, h = n >> 6, d = n & 63;
#pragma unroll
  for (int j = 0; j < 4; ++j) {
    int gm = mt * 16 + lhi * 4 + j;
    if (gm < 616) {
      int b = gm / 77, m = gm - b * 77;
      Kg[((size_t)(b * 16 + h) * 77 + m) * 64 + d] = (_Float16)ak[j];
      Vtg[((size_t)(b * 16 + h) * 64 + d) * 128 + m] = (_Float16)av[j];
    }
  }
}

// ====== 256x256 GEMM (R9 schedule) + fused attention epilogue (MODE 0) ======
// R19 = R17 champion, reverted after the R18 ring experiment (ring structure
// loses ~1.7x even bug-fixed: BM=128 doubles tile count; per-tile fixed
// overhead dominates at 1 block/CU). GEMM core: 16x16 frags, 3-bit conflict-
// free swizzle, INT-offset reads, true double-buffer, one vmcnt(0)+barrier per
// K-tile, cluster-ahead reads — 907 TF, session optimum across 5 structures.
// Epilogue (MODE 0): fused attention; kf/vf hoisted before Q-dump; P stored
// unnormalized, 1/sum folded into the output write; setprio on MFMA clusters.
// MODE 1 (O-proj): f32 out + bias.
template <int MODE>
__global__ __launch_bounds__(512, 2) void k_gemm9(const _Float16* __restrict__ A,
                                                  const _Float16* __restrict__ Bt,
                                                  void* __restrict__ Cout,
                                                  const float* __restrict__ bias,
                                                  const _Float16* __restrict__ Kg,
                                                  const _Float16* __restrict__ Vtg,
                                                  int M, int N, int K) {
  __shared__ __align__(16) char lds[MODE == 0 ? 163840 : 131072];
  const int t = threadIdx.x, wid = t >> 6, lane = t & 63;
  const int wr = wid >> 2, wc = wid & 3;  // 2M x 4N wave grid
  const int l15 = lane & 15, lhi = lane >> 4;

  // T1: bijective XCD swizzle (nwg % 8 == 0)
  int nwg = gridDim.x, bid = blockIdx.x;
  int wg = ((nwg & 7) == 0) ? ((bid & 7) * (nwg >> 3) + (bid >> 3)) : bid;
  const int nTN = N >> 8;
  const int tm = wg / nTN, tn = wg % nTN;

  const _Float16* Ag = A + (size_t)tm * 256 * K;
  const _Float16* Bg = Bt + (size_t)tn * 256 * K;
  const size_t stg = (size_t)(wid * 8 + (lane >> 3)) * K +
                     (size_t)(((lane & 7) ^ ((lane >> 3) & 7)) * 8);
  const int dstg = wid * 1024;

  const int x7 = l15 & 7;
  const int cs0 = (lhi ^ x7) << 4;
  const int cs1 = ((4 + lhi) ^ x7) << 4;
  const int aoff = wr * 16384 + l15 * 128;
  const int boff = 32768 + wc * 8192 + l15 * 128;

  f32x4 acc[8][4];
#pragma unroll
  for (int i = 0; i < 8; ++i)
#pragma unroll
    for (int j = 0; j < 4; ++j) acc[i][j] = f32x4{0.f, 0.f, 0.f, 0.f};
  f16x8 a0k0[4], a0k1[4], a1k0[4], a1k1[4];
  f16x8 b00[2], b01[2], b10[2], b11[2];

#define STG_A(T, RB) load_lds16(Ag + stg + (size_t)(RB) * K + (T) * 64, \
                                lds + ((T) & 1) * 65536 + (RB) * 128 + dstg)
#define STG_B(T, RB) load_lds16(Bg + stg + (size_t)(RB) * K + (T) * 64, \
                                lds + ((T) & 1) * 65536 + 32768 + (RB) * 128 + dstg)
#define STG_TILE(T) { STG_A(T, 0); STG_A(T, 64); STG_A(T, 128); STG_A(T, 192);  \
                      STG_B(T, 0); STG_B(T, 64); STG_B(T, 128); STG_B(T, 192); }
#define RDA(DST, BUF, MH, CS) { const int p_ = (BUF) * 65536 + aoff + (MH) * 8192; \
    _Pragma("unroll") for (int mf = 0; mf < 4; ++mf)                               \
      DST[mf] = *(const f16x8*)&lds[p_ + mf * 2048 + (CS)]; }
#define RDB(DST, BUF, NH, CS) { const int q_ = (BUF) * 65536 + boff + (NH) * 4096; \
    _Pragma("unroll") for (int nf = 0; nf < 2; ++nf)                               \
      DST[nf] = *(const f16x8*)&lds[q_ + nf * 2048 + (CS)]; }
#define MMC(MH, NH, AR, BR) { __builtin_amdgcn_s_setprio(1);                       \
    _Pragma("unroll") for (int mf = 0; mf < 4; ++mf)                               \
      _Pragma("unroll") for (int nf = 0; nf < 2; ++nf)                             \
        acc[(MH)*4+mf][(NH)*2+nf] = MFMA16(AR[mf], BR[nf],                         \
                                           acc[(MH)*4+mf][(NH)*2+nf]);             \
    __builtin_amdgcn_s_setprio(0); }
#define VM0 asm volatile("s_waitcnt vmcnt(0)" ::: "memory")
#define BAR __builtin_amdgcn_s_barrier()

#define TILE(BUF, T, STG_ON)                                                       \
  {                                                                                \
    VM0; BAR;                                                                      \
    RDA(a0k0, BUF, 0, cs0); RDB(b00, BUF, 0, cs0);                                 \
    RDB(b10, BUF, 1, cs0);                                                         \
    if (STG_ON) STG_TILE((T) + 1);                                                 \
    MMC(0, 0, a0k0, b00);                                                          \
    RDA(a1k0, BUF, 1, cs0); MMC(0, 1, a0k0, b10);                                  \
    RDA(a1k1, BUF, 1, cs1); MMC(1, 1, a1k0, b10);                                  \
    RDB(b01, BUF, 0, cs1);  MMC(1, 0, a1k0, b00);                                  \
    RDB(b11, BUF, 1, cs1);  MMC(1, 0, a1k1, b01);                                  \
    RDA(a0k1, BUF, 0, cs1); MMC(1, 1, a1k1, b11);                                  \
    MMC(0, 1, a0k1, b11);                                                          \
    MMC(0, 0, a0k1, b01);                                                          \
  }

  const int nT = K >> 6;

  STG_TILE(0);

  for (int i = 0; i < (nT >> 1) - 1; ++i) {
    TILE(0, 2 * i, true);
    TILE(1, 2 * i + 1, true);
  }
  TILE(0, nT - 2, true);
  TILE(1, nT - 1, false);

  if (MODE == 1) {
    // ---- plain epilogue: f32 + bias
    const long rbase = (long)tm * 256 + wr * 128;
    const int cbase = tn * 256 + wc * 64;
#pragma unroll
    for (int mf = 0; mf < 8; ++mf)
#pragma unroll
      for (int nf = 0; nf < 4; ++nf) {
        int c = cbase + nf * 16 + l15;
        float bv = bias[c];
#pragma unroll
        for (int j = 0; j < 4; ++j) {
          long r = rbase + mf * 16 + lhi * 4 + j;
          ((float*)Cout)[r * N + c] = acc[mf][nf][j] + bv;
        }
      }
    return;
  }

  // =================== MODE 0: fused attention epilogue ===================
  BAR;  // all waves done with K-loop LDS before repurposing

  const int h = tn * 4 + wc;
  const int bh = (tm >> 4) * 16 + h;
  const _Float16* Kgp = Kg + (size_t)bh * (77 * 64);
  const _Float16* Vgp = Vtg + (size_t)bh * (64 * 128);

  // issue mf-invariant K/V register loads FIRST so their global latency
  // hides under the Q-dump LDS writes below.
  f16x8 kf[5][2];
#pragma unroll
  for (int ct = 0; ct < 5; ++ct) {
    int m = ct * 16 + l15;
    kf[ct][0] = *(const f16x8*)(Kgp + m * 64 + lhi * 8);
    kf[ct][1] = *(const f16x8*)(Kgp + m * 64 + 32 + lhi * 8);
  }
  f16x8 vf[3][4];
#pragma unroll
  for (int ks = 0; ks < 3; ++ks)
#pragma unroll
    for (int dt = 0; dt < 4; ++dt) {
      int d = dt * 16 + l15;
      vf[ks][dt] = *(const f16x8*)(Vgp + d * 128 + ks * 32 + lhi * 8);
    }

  // dump Q (f32 acc -> f16) into per-wave 16KB LDS; acc is DEAD after this.
  const int qbase = wid * 16384;
#pragma unroll
  for (int mf = 0; mf < 8; ++mf)
#pragma unroll
    for (int nf = 0; nf < 4; ++nf)
#pragma unroll
      for (int j = 0; j < 4; ++j) {
        int row = mf * 16 + lhi * 4 + j;
        int d = nf * 16 + l15;
        int by = (row * 128 + d * 2) ^ ((row & 7) << 4);
        *(_Float16*)&lds[qbase + by] = (_Float16)acc[mf][nf][j];
      }

  // per-wave P region (4KB); zero once (covers m 80..95 pad)
  const int pbase = 131072 + wid * 4096;
#pragma unroll
  for (int i = 0; i < 4; ++i)
    *(f16x8*)&lds[pbase + lane * 64 + i * 16] = f16x8{};
  // wave-private below (lgkm ordering per wave); no barrier needed.

  const long orow0 = (long)tm * 256 + wr * 128;
  _Float16* aOut = (_Float16*)Cout;

  for (int mf = 0; mf < 8; ++mf) {
    const int qm = qbase + mf * 2048 + l15 * 128;
    f16x8 q0 = *(const f16x8*)&lds[qm + cs0];
    f16x8 q1 = *(const f16x8*)&lds[qm + cs1];

    float e[5][4];
    float mx[4] = {-1e30f, -1e30f, -1e30f, -1e30f};
    __builtin_amdgcn_s_setprio(1);
#pragma unroll
    for (int ct = 0; ct < 5; ++ct) {
      f32x4 s = {0.f, 0.f, 0.f, 0.f};
      s = MFMA16(q0, kf[ct][0], s);
      s = MFMA16(q1, kf[ct][1], s);
      bool valid = (ct * 16 + l15) < 77;
#pragma unroll
      for (int j = 0; j < 4; ++j) {
        float v = valid ? s[j] * 0.125f : -1e30f;
        e[ct][j] = v;
        mx[j] = fmaxf(mx[j], v);
      }
    }
    __builtin_amdgcn_s_setprio(0);
#pragma unroll
    for (int off = 1; off < 16; off <<= 1)
#pragma unroll
      for (int j = 0; j < 4; ++j) mx[j] = fmaxf(mx[j], __shfl_xor(mx[j], off, 64));

    // exp (unnormalized) + accumulate row-sum; write P = e immediately —
    // the sum reduce below overlaps with the P-writes/PV instead of gating them.
    float sm[4] = {0.f, 0.f, 0.f, 0.f};
#pragma unroll
    for (int ct = 0; ct < 5; ++ct)
#pragma unroll
      for (int j = 0; j < 4; ++j) {
        float ev = __expf(e[ct][j] - mx[j]);
        e[ct][j] = ev;
        sm[j] += ev;
      }
#pragma unroll
    for (int ct = 0; ct < 5; ++ct) {
      int m = ct * 16 + l15;
#pragma unroll
      for (int j = 0; j < 4; ++j) {
        int r = lhi * 4 + j;
        *(_Float16*)&lds[pbase + ((r * 256 + m * 2) ^ ((r & 7) << 4))] =
            (_Float16)e[ct][j];
      }
    }
#pragma unroll
    for (int off = 1; off < 16; off <<= 1)
#pragma unroll
      for (int j = 0; j < 4; ++j) sm[j] += __shfl_xor(sm[j], off, 64);
    float rs[4];
#pragma unroll
    for (int j = 0; j < 4; ++j) rs[j] = 1.0f / sm[j];

    // PV on unnormalized P; normalization folded into the output write.
    f32x4 o[4] = {{0.f,0.f,0.f,0.f},{0.f,0.f,0.f,0.f},{0.f,0.f,0.f,0.f},{0.f,0.f,0.f,0.f}};
    __builtin_amdgcn_s_setprio(1);
#pragma unroll
    for (int ks = 0; ks < 3; ++ks) {
      int m0b = ks * 64 + lhi * 16;
      f16x8 pa = *(const f16x8*)&lds[pbase + ((l15 * 256 + m0b) ^ ((l15 & 7) << 4))];
#pragma unroll
      for (int dt = 0; dt < 4; ++dt)
        o[dt] = MFMA16(pa, vf[ks][dt], o[dt]);
    }
    __builtin_amdgcn_s_setprio(0);
    _Float16* op = aOut + (size_t)(orow0 + mf * 16 + lhi * 4) * 1024 + h * 64;
#pragma unroll
    for (int dt = 0; dt < 4; ++dt)
#pragma unroll
      for (int j = 0; j < 4; ++j)
        op[(size_t)j * 1024 + dt * 16 + l15] = (_Float16)(o[dt][j] * rs[j]);
  }
#undef STG_A
#undef STG_B
#undef STG_TILE
#undef RDA
#undef RDB
#undef MMC
#undef TILE
#undef VM0
#undef BAR
}

extern "C" void kernel_launch(void* const* d_in, const int* in_sizes, int n_in,
                              void* d_out, int out_size, void* d_ws, size_t ws_size,
                              hipStream_t stream) {
  const float* x   = (const float*)d_in[0];
  const float* ctx = (const float*)d_in[1];
  const float* Wq  = (const float*)d_in[2];
  const float* Wk  = (const float*)d_in[3];
  const float* Wv  = (const float*)d_in[4];
  const float* Wo  = (const float*)d_in[5];
  const float* bo  = (const float*)d_in[6];

  // ws layout (145.9 MB total; ws>=146MB verified by R1/R2 bit-identical absmax)
  char* ws = (char*)d_ws;
  _Float16* xh   = (_Float16*)(ws + 0);           // [32768][1024] x-f16
  _Float16* Wqt  = (_Float16*)(ws + 67108864);    // [1024][1024]
  _Float16* Wkt  = (_Float16*)(ws + 69206016);    // [1024][768]
  _Float16* Wvt  = (_Float16*)(ws + 70778880);    // [1024][768]
  _Float16* Wot  = (_Float16*)(ws + 72351744);    // [1024][1024]
  _Float16* ctxh = (_Float16*)(ws + 74448896);    // [616][768]
  _Float16* Kg   = (_Float16*)(ws + 75395072);    // [128][77][64]
  _Float16* Vtg  = (_Float16*)(ws + 76656640);    // [128][64][128]
  _Float16* aOut = (_Float16*)(ws + 78774272);    // [32768][1024] attnOut

  k_prep<<<5735, 256, 0, stream>>>(x, ctx, Wq, Wk, Wv, Wo,
                                   xh, ctxh, Wqt, Wkt, Wvt, Wot, Vtg);
  k_kvproj<<<dim3(39, 64), 64, 0, stream>>>(ctxh, Wkt, Wvt, Kg, Vtg);
  // GEMM1 + fused attention: writes attnOut directly (no Qh round trip)
  k_gemm9<0><<<dim3(512), dim3(512), 0, stream>>>(xh, Wqt, (void*)aOut, nullptr,
                                                  Kg, Vtg, 32768, 1024, 1024);
  // GEMM2: O projection + bias -> d_out (f32)
  k_gemm9<1><<<dim3(512), dim3(512), 0, stream>>>(aOut, Wot, d_out, bo,
                                                  nullptr, nullptr, 32768, 1024, 1024);
}